// Round 1
// baseline (2838.158 us; speedup 1.0000x reference)
//
#include <hip/hip_runtime.h>

typedef __attribute__((ext_vector_type(8))) short bf16x8;
typedef __attribute__((ext_vector_type(4))) float f32x4;

__device__ __forceinline__ ushort f2b(float x) {
  union { float f; uint u; } v; v.f = x;
  uint u = v.u;
  u += 0x7fffu + ((u >> 16) & 1u);
  return (ushort)(u >> 16);
}
__device__ __forceinline__ float b2f(ushort x) {
  union { uint u; float f; } v; v.u = ((uint)x) << 16;
  return v.f;
}

// ---------------- fp32 -> bf16 conversion ----------------
__global__ __launch_bounds__(256) void cvt_kernel(const float* __restrict__ in,
                                                  ushort* __restrict__ out, int n4) {
  int i = blockIdx.x * 256 + threadIdx.x;
  if (i >= n4) return;
  float4 v = ((const float4*)in)[i];
  ushort4 o;
  o.x = f2b(v.x); o.y = f2b(v.y); o.z = f2b(v.z); o.w = f2b(v.w);
  ((ushort4*)out)[i] = o;
}

// ---------------- RoPE (in-place on bf16) ----------------
// layout: [token][head][128]; pairs (d, d+64); cos/sin: [token][128]
__global__ __launch_bounds__(256) void rope_kernel(ushort* __restrict__ q,
                                                   const float* __restrict__ cs,
                                                   const float* __restrict__ sn,
                                                   int n_heads, int total) {
  int idx = blockIdx.x * 256 + threadIdx.x;
  if (idx >= total) return;
  int d = idx & 63;
  int h = (idx >> 6) % n_heads;
  int tok = idx / (64 * n_heads);
  ushort* p = q + (size_t)tok * (n_heads * 128) + h * 128 + d;
  float c = cs[(size_t)tok * 128 + d];
  float s = sn[(size_t)tok * 128 + d];
  float x1 = b2f(p[0]);
  float x2 = b2f(p[64]);
  p[0]  = f2b(x1 * c - x2 * s);
  p[64] = f2b(x2 * c + x1 * s);
}

// ---------------- NT GEMM: C[m,n] = sum_k A[m,k] * B[n,k] ----------------
// A: MxK bf16 row-major, B: NxK bf16 row-major. C row-major (bf16 or fp32).
// tile 128x128x64, 256 threads = 4 waves (2x2 of 64x64 per wave).
__global__ __launch_bounds__(256) void gemm_nt(const ushort* __restrict__ A,
                                               const ushort* __restrict__ B,
                                               void* __restrict__ Cv,
                                               int M, int N, int K, int out_f32) {
  __shared__ ushort As[128 * 72];
  __shared__ ushort Bs[128 * 72];
  const int tid = threadIdx.x;
  const int m0 = blockIdx.x * 128;
  const int n0 = blockIdx.y * 128;
  const int wave = tid >> 6, lane = tid & 63;
  const int wm = (wave >> 1) * 64, wn = (wave & 1) * 64;
  const int lr = lane & 15, lq = lane >> 4;

  f32x4 acc[4][4] = {};

  const int srow = tid >> 3;           // 0..31
  const int skc = (tid & 7) * 8;       // 0..56

  for (int k0 = 0; k0 < K; k0 += 64) {
    for (int i = 0; i < 4; i++) {
      int r = srow + i * 32;
      uint4 va = *(const uint4*)(A + (size_t)(m0 + r) * K + k0 + skc);
      *(uint4*)(&As[r * 72 + skc]) = va;
      uint4 vb = *(const uint4*)(B + (size_t)(n0 + r) * K + k0 + skc);
      *(uint4*)(&Bs[r * 72 + skc]) = vb;
    }
    __syncthreads();
    for (int ks = 0; ks < 64; ks += 32) {
      bf16x8 af[4], bfv[4];
      for (int mi = 0; mi < 4; mi++)
        af[mi] = *(const bf16x8*)(&As[(wm + mi * 16 + lr) * 72 + ks + lq * 8]);
      for (int ni = 0; ni < 4; ni++)
        bfv[ni] = *(const bf16x8*)(&Bs[(wn + ni * 16 + lr) * 72 + ks + lq * 8]);
      for (int mi = 0; mi < 4; mi++)
        for (int ni = 0; ni < 4; ni++)
          acc[mi][ni] = __builtin_amdgcn_mfma_f32_16x16x32_bf16(af[mi], bfv[ni], acc[mi][ni], 0, 0, 0);
    }
    __syncthreads();
  }

  for (int mi = 0; mi < 4; mi++)
    for (int ni = 0; ni < 4; ni++)
      for (int r = 0; r < 4; r++) {
        int gm = m0 + wm + mi * 16 + lq * 4 + r;
        int gn = n0 + wn + ni * 16 + lr;
        float v = acc[mi][ni][r];
        if (out_f32) ((float*)Cv)[(size_t)gm * N + gn] = v;
        else ((ushort*)Cv)[(size_t)gm * N + gn] = f2b(v);
      }
}

// ---------------- causal flash attention ----------------
// Q: [tok][16*128] bf16 (rope'd), K/V: [tok][4*128] bf16, O: [tok][16*128] bf16
// grid: (qtile=16, head=16, batch=4), 256 threads = 4 waves, wave owns 32 q rows.
__global__ __launch_bounds__(256) void attn_kernel(const ushort* __restrict__ Q,
                                                   const ushort* __restrict__ Kb,
                                                   const ushort* __restrict__ Vb,
                                                   ushort* __restrict__ O) {
  constexpr int T = 2048;
  __shared__ ushort Ks[64][136];   // K tile: 64 kv x 128 d (padded)
  __shared__ ushort Vts[128][72];  // V^T tile: 128 d x 64 kv (padded)
  __shared__ ushort Ps[128][72];   // P: 128 q x 64 kv (padded)

  const int qt = blockIdx.x, h = blockIdx.y, b = blockIdx.z;
  const int kvh = h >> 2;
  const int tid = threadIdx.x, wave = tid >> 6, lane = tid & 63;
  const int lr = lane & 15, lq = lane >> 4;
  const int q0 = qt * 128;
  const size_t qbase = (size_t)b * T * 2048 + (size_t)h * 128;
  const size_t kvbase = (size_t)b * T * 512 + (size_t)kvh * 128;

  // Q fragments in registers: wave rows [wave*32, wave*32+32)
  bf16x8 qf[2][4];
  for (int mi = 0; mi < 2; mi++)
    for (int kx = 0; kx < 4; kx++) {
      int row = q0 + wave * 32 + mi * 16 + lr;
      qf[mi][kx] = *(const bf16x8*)(Q + qbase + (size_t)row * 2048 + kx * 32 + lq * 8);
    }

  float mstate[2][4], lstate[2][4];
  f32x4 oacc[2][8] = {};
  for (int mi = 0; mi < 2; mi++)
    for (int r = 0; r < 4; r++) { mstate[mi][r] = -__builtin_inff(); lstate[mi][r] = 0.f; }

  const float SC = 0.08838834764831845f * 1.4426950408889634f; // 1/sqrt(128) * log2(e)
  const int jmax = 2 * qt + 1;

  const int krow = tid >> 4, kc = (tid & 15) * 8;     // K staging
  const int vr = tid >> 2, vd0 = (tid & 3) * 2;       // V staging (transposed)

  for (int j = 0; j <= jmax; j++) {
    const int kv0 = j * 64;
    // stage K tile (coalesced)
    for (int i = 0; i < 4; i++) {
      int r = krow + i * 16;
      uint4 v = *(const uint4*)(Kb + kvbase + (size_t)(kv0 + r) * 512 + kc);
      *(uint4*)(&Ks[r][kc]) = v;
    }
    // stage V transposed
    for (int dd = 0; dd < 16; dd++) {
      int d = vd0 + dd * 8;
      uint v = *(const uint*)(Vb + kvbase + (size_t)(kv0 + vr) * 512 + d);
      Vts[d][vr] = (ushort)(v & 0xffffu);
      Vts[d + 1][vr] = (ushort)(v >> 16);
    }
    __syncthreads();

    // S = Q * K^T (32 x 64 per wave)
    f32x4 sacc[2][4] = {};
    for (int kx = 0; kx < 4; kx++) {
      bf16x8 kf[4];
      for (int ni = 0; ni < 4; ni++)
        kf[ni] = *(const bf16x8*)(&Ks[ni * 16 + lr][kx * 32 + lq * 8]);
      for (int mi = 0; mi < 2; mi++)
        for (int ni = 0; ni < 4; ni++)
          sacc[mi][ni] = __builtin_amdgcn_mfma_f32_16x16x32_bf16(qf[mi][kx], kf[ni], sacc[mi][ni], 0, 0, 0);
    }

    // online softmax per wave-owned rows
    for (int mi = 0; mi < 2; mi++) {
      float rmax[4];
      for (int r = 0; r < 4; r++) {
        int grow = q0 + wave * 32 + mi * 16 + lq * 4 + r;
        float mx = -__builtin_inff();
        for (int ni = 0; ni < 4; ni++) {
          float s = sacc[mi][ni][r] * SC;
          int gcol = kv0 + ni * 16 + lr;
          if (gcol > grow) s = -__builtin_inff();
          sacc[mi][ni][r] = s;
          mx = fmaxf(mx, s);
        }
        mx = fmaxf(mx, __shfl_xor(mx, 1));
        mx = fmaxf(mx, __shfl_xor(mx, 2));
        mx = fmaxf(mx, __shfl_xor(mx, 4));
        mx = fmaxf(mx, __shfl_xor(mx, 8));
        rmax[r] = mx;
      }
      for (int r = 0; r < 4; r++) {
        float mold = mstate[mi][r];
        float mnew = fmaxf(mold, rmax[r]);
        float alpha = exp2f(mold - mnew);
        float rs = 0.f;
        for (int ni = 0; ni < 4; ni++) {
          float p = exp2f(sacc[mi][ni][r] - mnew);
          sacc[mi][ni][r] = p;
          rs += p;
        }
        rs += __shfl_xor(rs, 1); rs += __shfl_xor(rs, 2);
        rs += __shfl_xor(rs, 4); rs += __shfl_xor(rs, 8);
        lstate[mi][r] = lstate[mi][r] * alpha + rs;
        mstate[mi][r] = mnew;
        for (int ni = 0; ni < 8; ni++) oacc[mi][ni][r] *= alpha;
      }
      // P -> LDS (C/D layout write); wave-private region, no barrier needed
      for (int ni = 0; ni < 4; ni++)
        for (int r = 0; r < 4; r++)
          Ps[wave * 32 + mi * 16 + lq * 4 + r][ni * 16 + lr] = f2b(sacc[mi][ni][r]);
    }

    // O += P * V  (P: 32x64 A-layout from LDS, V^T for B operand)
    for (int k2 = 0; k2 < 2; k2++) {
      bf16x8 pf[2];
      for (int mi = 0; mi < 2; mi++)
        pf[mi] = *(const bf16x8*)(&Ps[wave * 32 + mi * 16 + lr][k2 * 32 + lq * 8]);
      for (int ni = 0; ni < 8; ni++) {
        bf16x8 vf = *(const bf16x8*)(&Vts[ni * 16 + lr][k2 * 32 + lq * 8]);
        for (int mi = 0; mi < 2; mi++)
          oacc[mi][ni] = __builtin_amdgcn_mfma_f32_16x16x32_bf16(pf[mi], vf, oacc[mi][ni], 0, 0, 0);
      }
    }
    __syncthreads();
  }

  // epilogue: O /= l, write bf16
  for (int mi = 0; mi < 2; mi++)
    for (int r = 0; r < 4; r++) {
      float inv = 1.0f / lstate[mi][r];
      int grow = q0 + wave * 32 + mi * 16 + lq * 4 + r;
      size_t base = ((size_t)b * T + grow) * 2048 + (size_t)h * 128;
      for (int ni = 0; ni < 8; ni++)
        O[base + ni * 16 + lr] = f2b(oacc[mi][ni][r] * inv);
    }
}

// ---------------- launcher ----------------
extern "C" void kernel_launch(void* const* d_in, const int* in_sizes, int n_in,
                              void* d_out, int out_size, void* d_ws, size_t ws_size,
                              hipStream_t stream) {
  const float* hs   = (const float*)d_in[0];
  const float* cosp = (const float*)d_in[1];
  const float* sinp = (const float*)d_in[2];
  const float* wq   = (const float*)d_in[3];
  const float* wk   = (const float*)d_in[4];
  const float* wv   = (const float*)d_in[5];
  const float* wo   = (const float*)d_in[6];
  float* out = (float*)d_out;

  char* p = (char*)d_ws;
  ushort* hs_b = (ushort*)p; p += (size_t)8192 * 2048 * 2;
  ushort* q_b  = (ushort*)p; p += (size_t)8192 * 2048 * 2;
  ushort* k_b  = (ushort*)p; p += (size_t)8192 * 512 * 2;
  ushort* v_b  = (ushort*)p; p += (size_t)8192 * 512 * 2;
  ushort* o_b  = (ushort*)p; p += (size_t)8192 * 2048 * 2;
  ushort* wq_b = (ushort*)p; p += (size_t)2048 * 2048 * 2;
  ushort* wk_b = (ushort*)p; p += (size_t)512 * 2048 * 2;
  ushort* wv_b = (ushort*)p; p += (size_t)512 * 2048 * 2;
  ushort* wo_b = (ushort*)p; p += (size_t)2048 * 2048 * 2;

  // conversions
  cvt_kernel<<<16384, 256, 0, stream>>>(hs, hs_b, 4194304);
  cvt_kernel<<<4096, 256, 0, stream>>>(wq, wq_b, 1048576);
  cvt_kernel<<<1024, 256, 0, stream>>>(wk, wk_b, 262144);
  cvt_kernel<<<1024, 256, 0, stream>>>(wv, wv_b, 262144);
  cvt_kernel<<<4096, 256, 0, stream>>>(wo, wo_b, 1048576);

  // projections
  gemm_nt<<<dim3(64, 16), 256, 0, stream>>>(hs_b, wq_b, q_b, 8192, 2048, 2048, 0);
  gemm_nt<<<dim3(64, 4), 256, 0, stream>>>(hs_b, wk_b, k_b, 8192, 512, 2048, 0);
  gemm_nt<<<dim3(64, 4), 256, 0, stream>>>(hs_b, wv_b, v_b, 8192, 512, 2048, 0);

  // rope
  rope_kernel<<<32768, 256, 0, stream>>>(q_b, cosp, sinp, 16, 8388608);
  rope_kernel<<<8192, 256, 0, stream>>>(k_b, cosp, sinp, 4, 2097152);

  // attention
  attn_kernel<<<dim3(16, 16, 4), 256, 0, stream>>>(q_b, k_b, v_b, o_b);

  // output projection (fp32 out)
  gemm_nt<<<dim3(64, 16), 256, 0, stream>>>(o_b, wo_b, out, 8192, 2048, 2048, 1);
}

// Round 2
// 2506.430 us; speedup vs baseline: 1.1324x; 1.1324x over previous
//
#include <hip/hip_runtime.h>

typedef __attribute__((ext_vector_type(8))) short bf16x8;
typedef __attribute__((ext_vector_type(4))) float f32x4;

__device__ __forceinline__ ushort f2b(float x) {
  union { float f; uint u; } v; v.f = x;
  uint u = v.u;
  u += 0x7fffu + ((u >> 16) & 1u);
  return (ushort)(u >> 16);
}
__device__ __forceinline__ float b2f(ushort x) {
  union { uint u; float f; } v; v.u = ((uint)x) << 16;
  return v.f;
}

// ---------------- fp32 -> bf16 conversion ----------------
__global__ __launch_bounds__(256) void cvt_kernel(const float* __restrict__ in,
                                                  ushort* __restrict__ out, int n4) {
  int i = blockIdx.x * 256 + threadIdx.x;
  if (i >= n4) return;
  float4 v = ((const float4*)in)[i];
  ushort4 o;
  o.x = f2b(v.x); o.y = f2b(v.y); o.z = f2b(v.z); o.w = f2b(v.w);
  ((ushort4*)out)[i] = o;
}

// ---------------- RoPE (in-place on bf16) ----------------
// layout: [token][head][128]; pairs (d, d+64); cos/sin: [token][128]
__global__ __launch_bounds__(256) void rope_kernel(ushort* __restrict__ q,
                                                   const float* __restrict__ cs,
                                                   const float* __restrict__ sn,
                                                   int n_heads, int total) {
  int idx = blockIdx.x * 256 + threadIdx.x;
  if (idx >= total) return;
  int d = idx & 63;
  int h = (idx >> 6) % n_heads;
  int tok = idx / (64 * n_heads);
  ushort* p = q + (size_t)tok * (n_heads * 128) + h * 128 + d;
  float c = cs[(size_t)tok * 128 + d];
  float s = sn[(size_t)tok * 128 + d];
  float x1 = b2f(p[0]);
  float x2 = b2f(p[64]);
  p[0]  = f2b(x1 * c - x2 * s);
  p[64] = f2b(x2 * c + x1 * s);
}

// ---------------- NT GEMM: C[m,n] = sum_k A[m,k] * B[n,k] ----------------
// A: MxK bf16 row-major, B: NxK bf16 row-major. C row-major (bf16 or fp32).
// tile 128x128x64, 256 threads = 4 waves (2x2 of 64x64 per wave).
// __launch_bounds__(256,2): 2 blocks/CU -> 256 unified VGPR/lane budget; without
// it the allocator targeted 64 VGPR and spilled the 64-reg accumulator (R1: 3.1GB
// scratch writes, MfmaUtil 3%).
__global__ __launch_bounds__(256, 2) void gemm_nt(const ushort* __restrict__ A,
                                               const ushort* __restrict__ B,
                                               void* __restrict__ Cv,
                                               int M, int N, int K, int out_f32) {
  __shared__ ushort As[128 * 72];
  __shared__ ushort Bs[128 * 72];
  const int tid = threadIdx.x;
  const int m0 = blockIdx.x * 128;
  const int n0 = blockIdx.y * 128;
  const int wave = tid >> 6, lane = tid & 63;
  const int wm = (wave >> 1) * 64, wn = (wave & 1) * 64;
  const int lr = lane & 15, lq = lane >> 4;

  f32x4 acc[4][4] = {};

  const int srow = tid >> 3;           // 0..31
  const int skc = (tid & 7) * 8;       // 0..56

  for (int k0 = 0; k0 < K; k0 += 64) {
    for (int i = 0; i < 4; i++) {
      int r = srow + i * 32;
      uint4 va = *(const uint4*)(A + (size_t)(m0 + r) * K + k0 + skc);
      *(uint4*)(&As[r * 72 + skc]) = va;
      uint4 vb = *(const uint4*)(B + (size_t)(n0 + r) * K + k0 + skc);
      *(uint4*)(&Bs[r * 72 + skc]) = vb;
    }
    __syncthreads();
    for (int ks = 0; ks < 64; ks += 32) {
      bf16x8 af[4], bfv[4];
      for (int mi = 0; mi < 4; mi++)
        af[mi] = *(const bf16x8*)(&As[(wm + mi * 16 + lr) * 72 + ks + lq * 8]);
      for (int ni = 0; ni < 4; ni++)
        bfv[ni] = *(const bf16x8*)(&Bs[(wn + ni * 16 + lr) * 72 + ks + lq * 8]);
      for (int mi = 0; mi < 4; mi++)
        for (int ni = 0; ni < 4; ni++)
          acc[mi][ni] = __builtin_amdgcn_mfma_f32_16x16x32_bf16(af[mi], bfv[ni], acc[mi][ni], 0, 0, 0);
    }
    __syncthreads();
  }

  for (int mi = 0; mi < 4; mi++)
    for (int ni = 0; ni < 4; ni++)
      for (int r = 0; r < 4; r++) {
        int gm = m0 + wm + mi * 16 + lq * 4 + r;
        int gn = n0 + wn + ni * 16 + lr;
        float v = acc[mi][ni][r];
        if (out_f32) ((float*)Cv)[(size_t)gm * N + gn] = v;
        else ((ushort*)Cv)[(size_t)gm * N + gn] = f2b(v);
      }
}

// ---------------- causal flash attention ----------------
// Q: [tok][16*128] bf16 (rope'd), K/V: [tok][4*128] bf16, O: [tok][16*128] bf16
// grid: (qtile=16, head=16, batch=4), 256 threads = 4 waves, wave owns 32 q rows.
__global__ __launch_bounds__(256, 2) void attn_kernel(const ushort* __restrict__ Q,
                                                   const ushort* __restrict__ Kb,
                                                   const ushort* __restrict__ Vb,
                                                   ushort* __restrict__ O) {
  constexpr int T = 2048;
  __shared__ ushort Ks[64][136];   // K tile: 64 kv x 128 d (padded)
  __shared__ ushort Vts[128][72];  // V^T tile: 128 d x 64 kv (padded)
  __shared__ ushort Ps[128][72];   // P: 128 q x 64 kv (padded)

  const int qt = blockIdx.x, h = blockIdx.y, b = blockIdx.z;
  const int kvh = h >> 2;
  const int tid = threadIdx.x, wave = tid >> 6, lane = tid & 63;
  const int lr = lane & 15, lq = lane >> 4;
  const int q0 = qt * 128;
  const size_t qbase = (size_t)b * T * 2048 + (size_t)h * 128;
  const size_t kvbase = (size_t)b * T * 512 + (size_t)kvh * 128;

  // Q fragments in registers: wave rows [wave*32, wave*32+32)
  bf16x8 qf[2][4];
  for (int mi = 0; mi < 2; mi++)
    for (int kx = 0; kx < 4; kx++) {
      int row = q0 + wave * 32 + mi * 16 + lr;
      qf[mi][kx] = *(const bf16x8*)(Q + qbase + (size_t)row * 2048 + kx * 32 + lq * 8);
    }

  float mstate[2][4], lstate[2][4];
  f32x4 oacc[2][8] = {};
  for (int mi = 0; mi < 2; mi++)
    for (int r = 0; r < 4; r++) { mstate[mi][r] = -__builtin_inff(); lstate[mi][r] = 0.f; }

  const float SC = 0.08838834764831845f * 1.4426950408889634f; // 1/sqrt(128) * log2(e)
  const int jmax = 2 * qt + 1;

  const int krow = tid >> 4, kc = (tid & 15) * 8;     // K staging
  const int vr = tid >> 2, vd0 = (tid & 3) * 2;       // V staging (transposed)

  for (int j = 0; j <= jmax; j++) {
    const int kv0 = j * 64;
    // stage K tile (coalesced)
    for (int i = 0; i < 4; i++) {
      int r = krow + i * 16;
      uint4 v = *(const uint4*)(Kb + kvbase + (size_t)(kv0 + r) * 512 + kc);
      *(uint4*)(&Ks[r][kc]) = v;
    }
    // stage V transposed
    for (int dd = 0; dd < 16; dd++) {
      int d = vd0 + dd * 8;
      uint v = *(const uint*)(Vb + kvbase + (size_t)(kv0 + vr) * 512 + d);
      Vts[d][vr] = (ushort)(v & 0xffffu);
      Vts[d + 1][vr] = (ushort)(v >> 16);
    }
    __syncthreads();

    // S = Q * K^T (32 x 64 per wave)
    f32x4 sacc[2][4] = {};
    for (int kx = 0; kx < 4; kx++) {
      bf16x8 kf[4];
      for (int ni = 0; ni < 4; ni++)
        kf[ni] = *(const bf16x8*)(&Ks[ni * 16 + lr][kx * 32 + lq * 8]);
      for (int mi = 0; mi < 2; mi++)
        for (int ni = 0; ni < 4; ni++)
          sacc[mi][ni] = __builtin_amdgcn_mfma_f32_16x16x32_bf16(qf[mi][kx], kf[ni], sacc[mi][ni], 0, 0, 0);
    }

    // online softmax per wave-owned rows
    for (int mi = 0; mi < 2; mi++) {
      float rmax[4];
      for (int r = 0; r < 4; r++) {
        int grow = q0 + wave * 32 + mi * 16 + lq * 4 + r;
        float mx = -__builtin_inff();
        for (int ni = 0; ni < 4; ni++) {
          float s = sacc[mi][ni][r] * SC;
          int gcol = kv0 + ni * 16 + lr;
          if (gcol > grow) s = -__builtin_inff();
          sacc[mi][ni][r] = s;
          mx = fmaxf(mx, s);
        }
        mx = fmaxf(mx, __shfl_xor(mx, 1));
        mx = fmaxf(mx, __shfl_xor(mx, 2));
        mx = fmaxf(mx, __shfl_xor(mx, 4));
        mx = fmaxf(mx, __shfl_xor(mx, 8));
        rmax[r] = mx;
      }
      for (int r = 0; r < 4; r++) {
        float mold = mstate[mi][r];
        float mnew = fmaxf(mold, rmax[r]);
        float alpha = exp2f(mold - mnew);
        float rs = 0.f;
        for (int ni = 0; ni < 4; ni++) {
          float p = exp2f(sacc[mi][ni][r] - mnew);
          sacc[mi][ni][r] = p;
          rs += p;
        }
        rs += __shfl_xor(rs, 1); rs += __shfl_xor(rs, 2);
        rs += __shfl_xor(rs, 4); rs += __shfl_xor(rs, 8);
        lstate[mi][r] = lstate[mi][r] * alpha + rs;
        mstate[mi][r] = mnew;
        for (int ni = 0; ni < 8; ni++) oacc[mi][ni][r] *= alpha;
      }
      // P -> LDS (C/D layout write); wave-private region, no barrier needed
      for (int ni = 0; ni < 4; ni++)
        for (int r = 0; r < 4; r++)
          Ps[wave * 32 + mi * 16 + lq * 4 + r][ni * 16 + lr] = f2b(sacc[mi][ni][r]);
    }

    // O += P * V  (P: 32x64 A-layout from LDS, V^T for B operand)
    for (int k2 = 0; k2 < 2; k2++) {
      bf16x8 pf[2];
      for (int mi = 0; mi < 2; mi++)
        pf[mi] = *(const bf16x8*)(&Ps[wave * 32 + mi * 16 + lr][k2 * 32 + lq * 8]);
      for (int ni = 0; ni < 8; ni++) {
        bf16x8 vf = *(const bf16x8*)(&Vts[ni * 16 + lr][k2 * 32 + lq * 8]);
        for (int mi = 0; mi < 2; mi++)
          oacc[mi][ni] = __builtin_amdgcn_mfma_f32_16x16x32_bf16(pf[mi], vf, oacc[mi][ni], 0, 0, 0);
      }
    }
    __syncthreads();
  }

  // epilogue: O /= l, write bf16
  for (int mi = 0; mi < 2; mi++)
    for (int r = 0; r < 4; r++) {
      float inv = 1.0f / lstate[mi][r];
      int grow = q0 + wave * 32 + mi * 16 + lq * 4 + r;
      size_t base = ((size_t)b * T + grow) * 2048 + (size_t)h * 128;
      for (int ni = 0; ni < 8; ni++)
        O[base + ni * 16 + lr] = f2b(oacc[mi][ni][r] * inv);
    }
}

// ---------------- launcher ----------------
extern "C" void kernel_launch(void* const* d_in, const int* in_sizes, int n_in,
                              void* d_out, int out_size, void* d_ws, size_t ws_size,
                              hipStream_t stream) {
  const float* hs   = (const float*)d_in[0];
  const float* cosp = (const float*)d_in[1];
  const float* sinp = (const float*)d_in[2];
  const float* wq   = (const float*)d_in[3];
  const float* wk   = (const float*)d_in[4];
  const float* wv   = (const float*)d_in[5];
  const float* wo   = (const float*)d_in[6];
  float* out = (float*)d_out;

  char* p = (char*)d_ws;
  ushort* hs_b = (ushort*)p; p += (size_t)8192 * 2048 * 2;
  ushort* q_b  = (ushort*)p; p += (size_t)8192 * 2048 * 2;
  ushort* k_b  = (ushort*)p; p += (size_t)8192 * 512 * 2;
  ushort* v_b  = (ushort*)p; p += (size_t)8192 * 512 * 2;
  ushort* o_b  = (ushort*)p; p += (size_t)8192 * 2048 * 2;
  ushort* wq_b = (ushort*)p; p += (size_t)2048 * 2048 * 2;
  ushort* wk_b = (ushort*)p; p += (size_t)512 * 2048 * 2;
  ushort* wv_b = (ushort*)p; p += (size_t)512 * 2048 * 2;
  ushort* wo_b = (ushort*)p; p += (size_t)2048 * 2048 * 2;

  // conversions
  cvt_kernel<<<16384, 256, 0, stream>>>(hs, hs_b, 4194304);
  cvt_kernel<<<4096, 256, 0, stream>>>(wq, wq_b, 1048576);
  cvt_kernel<<<1024, 256, 0, stream>>>(wk, wk_b, 262144);
  cvt_kernel<<<1024, 256, 0, stream>>>(wv, wv_b, 262144);
  cvt_kernel<<<4096, 256, 0, stream>>>(wo, wo_b, 1048576);

  // projections
  gemm_nt<<<dim3(64, 16), 256, 0, stream>>>(hs_b, wq_b, q_b, 8192, 2048, 2048, 0);
  gemm_nt<<<dim3(64, 4), 256, 0, stream>>>(hs_b, wk_b, k_b, 8192, 512, 2048, 0);
  gemm_nt<<<dim3(64, 4), 256, 0, stream>>>(hs_b, wv_b, v_b, 8192, 512, 2048, 0);

  // rope
  rope_kernel<<<32768, 256, 0, stream>>>(q_b, cosp, sinp, 16, 8388608);
  rope_kernel<<<8192, 256, 0, stream>>>(k_b, cosp, sinp, 4, 2097152);

  // attention
  attn_kernel<<<dim3(16, 16, 4), 256, 0, stream>>>(q_b, k_b, v_b, o_b);

  // output projection (fp32 out)
  gemm_nt<<<dim3(64, 16), 256, 0, stream>>>(o_b, wo_b, out, 8192, 2048, 2048, 1);
}

// Round 3
// 2457.736 us; speedup vs baseline: 1.1548x; 1.0198x over previous
//
#include <hip/hip_runtime.h>

typedef __attribute__((ext_vector_type(8))) short bf16x8;
typedef __attribute__((ext_vector_type(4))) float f32x4;

__device__ __forceinline__ ushort f2b(float x) {
  union { float f; uint u; } v; v.f = x;
  uint u = v.u;
  u += 0x7fffu + ((u >> 16) & 1u);
  return (ushort)(u >> 16);
}
__device__ __forceinline__ float b2f(ushort x) {
  union { uint u; float f; } v; v.u = ((uint)x) << 16;
  return v.f;
}

// async global->LDS, 16B per lane; lds base must be wave-uniform (HW scatters lane*16)
__device__ __forceinline__ void async16(const ushort* g, ushort* l) {
  __builtin_amdgcn_global_load_lds(
      (const __attribute__((address_space(1))) unsigned int*)g,
      (__attribute__((address_space(3))) unsigned int*)l, 16, 0, 0);
}

// ---------------- fp32 -> bf16 conversion ----------------
__global__ __launch_bounds__(256) void cvt_kernel(const float* __restrict__ in,
                                                  ushort* __restrict__ out, int n4) {
  int i = blockIdx.x * 256 + threadIdx.x;
  if (i >= n4) return;
  float4 v = ((const float4*)in)[i];
  ushort4 o;
  o.x = f2b(v.x); o.y = f2b(v.y); o.z = f2b(v.z); o.w = f2b(v.w);
  ((ushort4*)out)[i] = o;
}

// ---------------- RoPE (in-place on bf16) ----------------
__global__ __launch_bounds__(256) void rope_kernel(ushort* __restrict__ q,
                                                   const float* __restrict__ cs,
                                                   const float* __restrict__ sn,
                                                   int n_heads, int total) {
  int idx = blockIdx.x * 256 + threadIdx.x;
  if (idx >= total) return;
  int d = idx & 63;
  int h = (idx >> 6) % n_heads;
  int tok = idx / (64 * n_heads);
  ushort* p = q + (size_t)tok * (n_heads * 128) + h * 128 + d;
  float c = cs[(size_t)tok * 128 + d];
  float s = sn[(size_t)tok * 128 + d];
  float x1 = b2f(p[0]);
  float x2 = b2f(p[64]);
  p[0]  = f2b(x1 * c - x2 * s);
  p[64] = f2b(x2 * c + x1 * s);
}

// ---------------- NT GEMM: C[m,n] = sum_k A[m,k] * B[n,k] ----------------
// 128x128x64 tile, 4 waves (2x2 of 64x64). global_load_lds width-16 staging.
// LDS unpadded [128][64] ushort; bank conflicts broken by XOR-swizzling the
// GLOBAL source chunk (chunk ^ (row&7)) since the LDS lane->slot map is fixed.
// __launch_bounds__(256,1): R2 showed the allocator spilling acc (3.1GB scratch
// writes, MfmaUtil 3%) when targeting higher occupancy.
__global__ __launch_bounds__(256, 1) void gemm_nt(const ushort* __restrict__ A,
                                                  const ushort* __restrict__ B,
                                                  void* __restrict__ Cv,
                                                  int M, int N, int K, int out_f32) {
  __shared__ __align__(16) ushort As[128 * 64];
  __shared__ __align__(16) ushort Bs[128 * 64];
  const int tid = threadIdx.x;
  const int m0 = blockIdx.x * 128;
  const int n0 = blockIdx.y * 128;
  const int wave = tid >> 6, lane = tid & 63;
  const int wm = (wave >> 1) * 64, wn = (wave & 1) * 64;
  const int lr = lane & 15, lq = lane >> 4;

  // staging geometry: issue (i,wave) fills LDS chunk c16 = i*4+wave (8 rows x 64 cols);
  // lane -> row = c16*8 + (lane>>3), slot pos = lane&7, holds global chunk pos^(row&7)
  const int rsub = lane >> 3;     // 0..7
  const int pos = lane & 7;
  const int cg = pos ^ rsub;      // swizzled global 8-ushort chunk index

  // fragment LDS offsets (loop-invariant): read chunk c = ks*4+lq of row,
  // stored at position c ^ (row&7); row&7 == lr&7 here.
  int offA[4][2], offB[4][2];
  for (int mi = 0; mi < 4; mi++)
    for (int ks = 0; ks < 2; ks++) {
      int c = ks * 4 + lq;
      int sw = (c ^ (lr & 7)) * 8;
      offA[mi][ks] = (wm + mi * 16 + lr) * 64 + sw;
      offB[mi][ks] = (wn + mi * 16 + lr) * 64 + sw;
    }

  f32x4 acc[4][4] = {};

  for (int k0 = 0; k0 < K; k0 += 64) {
    for (int i = 0; i < 4; i++) {
      int c16 = i * 4 + wave;
      int row = c16 * 8 + rsub;
      async16(A + (size_t)(m0 + row) * K + k0 + cg * 8, &As[c16 * 512]);
      async16(B + (size_t)(n0 + row) * K + k0 + cg * 8, &Bs[c16 * 512]);
    }
    __syncthreads();
    for (int ks = 0; ks < 2; ks++) {
      bf16x8 af[4], bfv[4];
      for (int mi = 0; mi < 4; mi++) af[mi] = *(const bf16x8*)(&As[offA[mi][ks]]);
      for (int ni = 0; ni < 4; ni++) bfv[ni] = *(const bf16x8*)(&Bs[offB[ni][ks]]);
      for (int mi = 0; mi < 4; mi++)
        for (int ni = 0; ni < 4; ni++)
          acc[mi][ni] = __builtin_amdgcn_mfma_f32_16x16x32_bf16(af[mi], bfv[ni], acc[mi][ni], 0, 0, 0);
    }
    __syncthreads();
  }

  for (int mi = 0; mi < 4; mi++)
    for (int ni = 0; ni < 4; ni++)
      for (int r = 0; r < 4; r++) {
        int gm = m0 + wm + mi * 16 + lq * 4 + r;
        int gn = n0 + wn + ni * 16 + lr;
        float v = acc[mi][ni][r];
        if (out_f32) ((float*)Cv)[(size_t)gm * N + gn] = v;
        else ((ushort*)Cv)[(size_t)gm * N + gn] = f2b(v);
      }
}

// ---------------- causal flash attention ----------------
// Q: [tok][16*128] bf16 (rope'd), K/V: [tok][4*128] bf16, O: [tok][16*128] bf16
// grid: (qtile=16, head=16, batch=4), 256 threads = 4 waves, wave owns 32 q rows.
__global__ __launch_bounds__(256, 1) void attn_kernel(const ushort* __restrict__ Q,
                                                   const ushort* __restrict__ Kb,
                                                   const ushort* __restrict__ Vb,
                                                   ushort* __restrict__ O) {
  constexpr int T = 2048;
  __shared__ ushort Ks[64][136];   // K tile: 64 kv x 128 d (padded)
  __shared__ ushort Vts[128][72];  // V^T tile: 128 d x 64 kv (padded)
  __shared__ ushort Ps[128][72];   // P: 128 q x 64 kv (padded)

  const int qt = blockIdx.x, h = blockIdx.y, b = blockIdx.z;
  const int kvh = h >> 2;
  const int tid = threadIdx.x, wave = tid >> 6, lane = tid & 63;
  const int lr = lane & 15, lq = lane >> 4;
  const int q0 = qt * 128;
  const size_t qbase = (size_t)b * T * 2048 + (size_t)h * 128;
  const size_t kvbase = (size_t)b * T * 512 + (size_t)kvh * 128;

  // Q fragments in registers: wave rows [wave*32, wave*32+32)
  bf16x8 qf[2][4];
  for (int mi = 0; mi < 2; mi++)
    for (int kx = 0; kx < 4; kx++) {
      int row = q0 + wave * 32 + mi * 16 + lr;
      qf[mi][kx] = *(const bf16x8*)(Q + qbase + (size_t)row * 2048 + kx * 32 + lq * 8);
    }

  float mstate[2][4], lstate[2][4];
  f32x4 oacc[2][8] = {};
  for (int mi = 0; mi < 2; mi++)
    for (int r = 0; r < 4; r++) { mstate[mi][r] = -__builtin_inff(); lstate[mi][r] = 0.f; }

  const float SC = 0.08838834764831845f * 1.4426950408889634f; // 1/sqrt(128) * log2(e)
  const int jmax = 2 * qt + 1;

  const int krow = tid >> 4, kc = (tid & 15) * 8;     // K staging
  const int vr = tid >> 2, vd0 = (tid & 3) * 2;       // V staging (transposed)

  for (int j = 0; j <= jmax; j++) {
    const int kv0 = j * 64;
    // stage K tile (coalesced)
    for (int i = 0; i < 4; i++) {
      int r = krow + i * 16;
      uint4 v = *(const uint4*)(Kb + kvbase + (size_t)(kv0 + r) * 512 + kc);
      *(uint4*)(&Ks[r][kc]) = v;
    }
    // stage V transposed
    for (int dd = 0; dd < 16; dd++) {
      int d = vd0 + dd * 8;
      uint v = *(const uint*)(Vb + kvbase + (size_t)(kv0 + vr) * 512 + d);
      Vts[d][vr] = (ushort)(v & 0xffffu);
      Vts[d + 1][vr] = (ushort)(v >> 16);
    }
    __syncthreads();

    // S = Q * K^T (32 x 64 per wave)
    f32x4 sacc[2][4] = {};
    for (int kx = 0; kx < 4; kx++) {
      bf16x8 kf[4];
      for (int ni = 0; ni < 4; ni++)
        kf[ni] = *(const bf16x8*)(&Ks[ni * 16 + lr][kx * 32 + lq * 8]);
      for (int mi = 0; mi < 2; mi++)
        for (int ni = 0; ni < 4; ni++)
          sacc[mi][ni] = __builtin_amdgcn_mfma_f32_16x16x32_bf16(qf[mi][kx], kf[ni], sacc[mi][ni], 0, 0, 0);
    }

    // online softmax per wave-owned rows
    for (int mi = 0; mi < 2; mi++) {
      float rmax[4];
      for (int r = 0; r < 4; r++) {
        int grow = q0 + wave * 32 + mi * 16 + lq * 4 + r;
        float mx = -__builtin_inff();
        for (int ni = 0; ni < 4; ni++) {
          float s = sacc[mi][ni][r] * SC;
          int gcol = kv0 + ni * 16 + lr;
          if (gcol > grow) s = -__builtin_inff();
          sacc[mi][ni][r] = s;
          mx = fmaxf(mx, s);
        }
        mx = fmaxf(mx, __shfl_xor(mx, 1));
        mx = fmaxf(mx, __shfl_xor(mx, 2));
        mx = fmaxf(mx, __shfl_xor(mx, 4));
        mx = fmaxf(mx, __shfl_xor(mx, 8));
        rmax[r] = mx;
      }
      for (int r = 0; r < 4; r++) {
        float mold = mstate[mi][r];
        float mnew = fmaxf(mold, rmax[r]);
        float alpha = exp2f(mold - mnew);
        float rs = 0.f;
        for (int ni = 0; ni < 4; ni++) {
          float p = exp2f(sacc[mi][ni][r] - mnew);
          sacc[mi][ni][r] = p;
          rs += p;
        }
        rs += __shfl_xor(rs, 1); rs += __shfl_xor(rs, 2);
        rs += __shfl_xor(rs, 4); rs += __shfl_xor(rs, 8);
        lstate[mi][r] = lstate[mi][r] * alpha + rs;
        mstate[mi][r] = mnew;
        for (int ni = 0; ni < 8; ni++) oacc[mi][ni][r] *= alpha;
      }
      // P -> LDS (C/D layout write); wave-private region, no barrier needed
      for (int ni = 0; ni < 4; ni++)
        for (int r = 0; r < 4; r++)
          Ps[wave * 32 + mi * 16 + lq * 4 + r][ni * 16 + lr] = f2b(sacc[mi][ni][r]);
    }

    // O += P * V  (P: 32x64 A-layout from LDS, V^T for B operand)
    for (int k2 = 0; k2 < 2; k2++) {
      bf16x8 pf[2];
      for (int mi = 0; mi < 2; mi++)
        pf[mi] = *(const bf16x8*)(&Ps[wave * 32 + mi * 16 + lr][k2 * 32 + lq * 8]);
      for (int ni = 0; ni < 8; ni++) {
        bf16x8 vf = *(const bf16x8*)(&Vts[ni * 16 + lr][k2 * 32 + lq * 8]);
        for (int mi = 0; mi < 2; mi++)
          oacc[mi][ni] = __builtin_amdgcn_mfma_f32_16x16x32_bf16(pf[mi], vf, oacc[mi][ni], 0, 0, 0);
      }
    }
    __syncthreads();
  }

  // epilogue: O /= l, write bf16
  for (int mi = 0; mi < 2; mi++)
    for (int r = 0; r < 4; r++) {
      float inv = 1.0f / lstate[mi][r];
      int grow = q0 + wave * 32 + mi * 16 + lq * 4 + r;
      size_t base = ((size_t)b * T + grow) * 2048 + (size_t)h * 128;
      for (int ni = 0; ni < 8; ni++)
        O[base + ni * 16 + lr] = f2b(oacc[mi][ni][r] * inv);
    }
}

// ---------------- launcher ----------------
extern "C" void kernel_launch(void* const* d_in, const int* in_sizes, int n_in,
                              void* d_out, int out_size, void* d_ws, size_t ws_size,
                              hipStream_t stream) {
  const float* hs   = (const float*)d_in[0];
  const float* cosp = (const float*)d_in[1];
  const float* sinp = (const float*)d_in[2];
  const float* wq   = (const float*)d_in[3];
  const float* wk   = (const float*)d_in[4];
  const float* wv   = (const float*)d_in[5];
  const float* wo   = (const float*)d_in[6];
  float* out = (float*)d_out;

  char* p = (char*)d_ws;
  ushort* hs_b = (ushort*)p; p += (size_t)8192 * 2048 * 2;
  ushort* q_b  = (ushort*)p; p += (size_t)8192 * 2048 * 2;
  ushort* k_b  = (ushort*)p; p += (size_t)8192 * 512 * 2;
  ushort* v_b  = (ushort*)p; p += (size_t)8192 * 512 * 2;
  ushort* o_b  = (ushort*)p; p += (size_t)8192 * 2048 * 2;
  ushort* wq_b = (ushort*)p; p += (size_t)2048 * 2048 * 2;
  ushort* wk_b = (ushort*)p; p += (size_t)512 * 2048 * 2;
  ushort* wv_b = (ushort*)p; p += (size_t)512 * 2048 * 2;
  ushort* wo_b = (ushort*)p; p += (size_t)2048 * 2048 * 2;

  // conversions
  cvt_kernel<<<16384, 256, 0, stream>>>(hs, hs_b, 4194304);
  cvt_kernel<<<4096, 256, 0, stream>>>(wq, wq_b, 1048576);
  cvt_kernel<<<1024, 256, 0, stream>>>(wk, wk_b, 262144);
  cvt_kernel<<<1024, 256, 0, stream>>>(wv, wv_b, 262144);
  cvt_kernel<<<4096, 256, 0, stream>>>(wo, wo_b, 1048576);

  // projections
  gemm_nt<<<dim3(64, 16), 256, 0, stream>>>(hs_b, wq_b, q_b, 8192, 2048, 2048, 0);
  gemm_nt<<<dim3(64, 4), 256, 0, stream>>>(hs_b, wk_b, k_b, 8192, 512, 2048, 0);
  gemm_nt<<<dim3(64, 4), 256, 0, stream>>>(hs_b, wv_b, v_b, 8192, 512, 2048, 0);

  // rope
  rope_kernel<<<32768, 256, 0, stream>>>(q_b, cosp, sinp, 16, 8388608);
  rope_kernel<<<8192, 256, 0, stream>>>(k_b, cosp, sinp, 4, 2097152);

  // attention
  attn_kernel<<<dim3(16, 16, 4), 256, 0, stream>>>(q_b, k_b, v_b, o_b);

  // output projection (fp32 out)
  gemm_nt<<<dim3(64, 16), 256, 0, stream>>>(o_b, wo_b, out, 8192, 2048, 2048, 1);
}

// Round 5
// 765.586 us; speedup vs baseline: 3.7072x; 3.2103x over previous
//
#include <hip/hip_runtime.h>

typedef __attribute__((ext_vector_type(8))) short bf16x8;
typedef __attribute__((ext_vector_type(4))) float f32x4;

__device__ __forceinline__ ushort f2b(float x) {
  union { float f; uint u; } v; v.f = x;
  uint u = v.u;
  u += 0x7fffu + ((u >> 16) & 1u);
  return (ushort)(u >> 16);
}
__device__ __forceinline__ float b2f(ushort x) {
  union { uint u; float f; } v; v.u = ((uint)x) << 16;
  return v.f;
}

// async global->LDS, 16B per lane; lds base must be wave-uniform (HW scatters lane*16)
__device__ __forceinline__ void async16(const ushort* g, ushort* l) {
  __builtin_amdgcn_global_load_lds(
      (const __attribute__((address_space(1))) unsigned int*)g,
      (__attribute__((address_space(3))) unsigned int*)l, 16, 0, 0);
}

// ---------------- fp32 -> bf16 conversion ----------------
__global__ __launch_bounds__(256) void cvt_kernel(const float* __restrict__ in,
                                                  ushort* __restrict__ out, int n4) {
  int i = blockIdx.x * 256 + threadIdx.x;
  if (i >= n4) return;
  float4 v = ((const float4*)in)[i];
  ushort4 o;
  o.x = f2b(v.x); o.y = f2b(v.y); o.z = f2b(v.z); o.w = f2b(v.w);
  ((ushort4*)out)[i] = o;
}

// ---------------- RoPE (in-place on bf16) ----------------
__global__ __launch_bounds__(256) void rope_kernel(ushort* __restrict__ q,
                                                   const float* __restrict__ cs,
                                                   const float* __restrict__ sn,
                                                   int n_heads, int total) {
  int idx = blockIdx.x * 256 + threadIdx.x;
  if (idx >= total) return;
  int d = idx & 63;
  int h = (idx >> 6) % n_heads;
  int tok = idx / (64 * n_heads);
  ushort* p = q + (size_t)tok * (n_heads * 128) + h * 128 + d;
  float c = cs[(size_t)tok * 128 + d];
  float s = sn[(size_t)tok * 128 + d];
  float x1 = b2f(p[0]);
  float x2 = b2f(p[64]);
  p[0]  = f2b(x1 * c - x2 * s);
  p[64] = f2b(x2 * c + x1 * s);
}

// ---------------- NT GEMM: C[m,n] = sum_k A[m,k] * B[n,k] ----------------
// 128x128x64 tile, 4 waves (2x2 of 64x64). global_load_lds width-16 staging.
// R3 lesson: acc[4][4] must be fully unroll-indexed or it lives in scratch.
// R4 lesson: the LDS-DMA -> __syncthreads() edge needs an EXPLICIT
// s_waitcnt vmcnt(0); relying on the compiler's barrier drain raced
// intermittently under graph replay (post-timing absmax 0.248).
template <bool OUT_F32>
__global__ __launch_bounds__(256, 1) void gemm_nt(const ushort* __restrict__ A,
                                                  const ushort* __restrict__ B,
                                                  void* __restrict__ Cv,
                                                  int M, int N, int K) {
  __shared__ __align__(16) ushort As[128 * 64];
  __shared__ __align__(16) ushort Bs[128 * 64];
  const int tid = threadIdx.x;
  const int m0 = blockIdx.x * 128;
  const int n0 = blockIdx.y * 128;
  const int wave = tid >> 6, lane = tid & 63;
  const int wm = (wave >> 1) * 64, wn = (wave & 1) * 64;
  const int lr = lane & 15, lq = lane >> 4;

  // staging geometry: issue (i,wave) fills LDS chunk c16 = i*4+wave (8 rows x 64 cols);
  // lane -> row = c16*8 + (lane>>3), slot pos = lane&7, holds global chunk pos^(row&7)
  const int rsub = lane >> 3;     // 0..7
  const int pos = lane & 7;
  const int cg = pos ^ rsub;      // swizzled global 8-ushort chunk index

  // fragment LDS offsets (loop-invariant): read chunk c = ks*4+lq of row,
  // stored at position c ^ (row&7); row&7 == lr&7 here.
  int offA[4][2], offB[4][2];
#pragma unroll
  for (int mi = 0; mi < 4; mi++)
#pragma unroll
    for (int ks = 0; ks < 2; ks++) {
      int c = ks * 4 + lq;
      int sw = (c ^ (lr & 7)) * 8;
      offA[mi][ks] = (wm + mi * 16 + lr) * 64 + sw;
      offB[mi][ks] = (wn + mi * 16 + lr) * 64 + sw;
    }

  f32x4 acc[4][4] = {};

  for (int k0 = 0; k0 < K; k0 += 64) {
#pragma unroll
    for (int i = 0; i < 4; i++) {
      int c16 = i * 4 + wave;
      int row = c16 * 8 + rsub;
      async16(A + (size_t)(m0 + row) * K + k0 + cg * 8, &As[c16 * 512]);
      async16(B + (size_t)(n0 + row) * K + k0 + cg * 8, &Bs[c16 * 512]);
    }
    // explicit drain of the LDS-DMA before the barrier (see R4 note above)
    asm volatile("s_waitcnt vmcnt(0)" ::: "memory");
    __syncthreads();
#pragma unroll
    for (int ks = 0; ks < 2; ks++) {
      bf16x8 af[4], bfv[4];
#pragma unroll
      for (int mi = 0; mi < 4; mi++) af[mi] = *(const bf16x8*)(&As[offA[mi][ks]]);
#pragma unroll
      for (int ni = 0; ni < 4; ni++) bfv[ni] = *(const bf16x8*)(&Bs[offB[ni][ks]]);
#pragma unroll
      for (int mi = 0; mi < 4; mi++)
#pragma unroll
        for (int ni = 0; ni < 4; ni++)
          acc[mi][ni] = __builtin_amdgcn_mfma_f32_16x16x32_bf16(af[mi], bfv[ni], acc[mi][ni], 0, 0, 0);
    }
    __syncthreads();
  }

#pragma unroll
  for (int mi = 0; mi < 4; mi++)
#pragma unroll
    for (int ni = 0; ni < 4; ni++)
#pragma unroll
      for (int r = 0; r < 4; r++) {
        int gm = m0 + wm + mi * 16 + lq * 4 + r;
        int gn = n0 + wn + ni * 16 + lr;
        float v = acc[mi][ni][r];
        if (OUT_F32) ((float*)Cv)[(size_t)gm * N + gn] = v;
        else ((ushort*)Cv)[(size_t)gm * N + gn] = f2b(v);
      }
}

// ---------------- causal flash attention ----------------
// Q: [tok][16*128] bf16 (rope'd), K/V: [tok][4*128] bf16, O: [tok][16*128] bf16
// grid: (qtile=16, head=16, batch=4), 256 threads = 4 waves, wave owns 32 q rows.
__global__ __launch_bounds__(256, 1) void attn_kernel(const ushort* __restrict__ Q,
                                                   const ushort* __restrict__ Kb,
                                                   const ushort* __restrict__ Vb,
                                                   ushort* __restrict__ O) {
  constexpr int T = 2048;
  __shared__ ushort Ks[64][136];   // K tile: 64 kv x 128 d (padded)
  __shared__ ushort Vts[128][72];  // V^T tile: 128 d x 64 kv (padded)
  __shared__ ushort Ps[128][72];   // P: 128 q x 64 kv (padded)

  const int qt = blockIdx.x, h = blockIdx.y, b = blockIdx.z;
  const int kvh = h >> 2;
  const int tid = threadIdx.x, wave = tid >> 6, lane = tid & 63;
  const int lr = lane & 15, lq = lane >> 4;
  const int q0 = qt * 128;
  const size_t qbase = (size_t)b * T * 2048 + (size_t)h * 128;
  const size_t kvbase = (size_t)b * T * 512 + (size_t)kvh * 128;

  // Q fragments in registers: wave rows [wave*32, wave*32+32)
  bf16x8 qf[2][4];
#pragma unroll
  for (int mi = 0; mi < 2; mi++)
#pragma unroll
    for (int kx = 0; kx < 4; kx++) {
      int row = q0 + wave * 32 + mi * 16 + lr;
      qf[mi][kx] = *(const bf16x8*)(Q + qbase + (size_t)row * 2048 + kx * 32 + lq * 8);
    }

  float mstate[2][4], lstate[2][4];
  f32x4 oacc[2][8] = {};
#pragma unroll
  for (int mi = 0; mi < 2; mi++)
#pragma unroll
    for (int r = 0; r < 4; r++) { mstate[mi][r] = -__builtin_inff(); lstate[mi][r] = 0.f; }

  const float SC = 0.08838834764831845f * 1.4426950408889634f; // 1/sqrt(128) * log2(e)
  const int jmax = 2 * qt + 1;

  const int krow = tid >> 4, kc = (tid & 15) * 8;     // K staging
  const int vr = tid >> 2, vd0 = (tid & 3) * 2;       // V staging (transposed)

  for (int j = 0; j <= jmax; j++) {
    const int kv0 = j * 64;
    // stage K tile (coalesced)
#pragma unroll
    for (int i = 0; i < 4; i++) {
      int r = krow + i * 16;
      uint4 v = *(const uint4*)(Kb + kvbase + (size_t)(kv0 + r) * 512 + kc);
      *(uint4*)(&Ks[r][kc]) = v;
    }
    // stage V transposed
#pragma unroll
    for (int dd = 0; dd < 16; dd++) {
      int d = vd0 + dd * 8;
      uint v = *(const uint*)(Vb + kvbase + (size_t)(kv0 + vr) * 512 + d);
      Vts[d][vr] = (ushort)(v & 0xffffu);
      Vts[d + 1][vr] = (ushort)(v >> 16);
    }
    __syncthreads();

    // S = Q * K^T (32 x 64 per wave)
    f32x4 sacc[2][4] = {};
#pragma unroll
    for (int kx = 0; kx < 4; kx++) {
      bf16x8 kf[4];
#pragma unroll
      for (int ni = 0; ni < 4; ni++)
        kf[ni] = *(const bf16x8*)(&Ks[ni * 16 + lr][kx * 32 + lq * 8]);
#pragma unroll
      for (int mi = 0; mi < 2; mi++)
#pragma unroll
        for (int ni = 0; ni < 4; ni++)
          sacc[mi][ni] = __builtin_amdgcn_mfma_f32_16x16x32_bf16(qf[mi][kx], kf[ni], sacc[mi][ni], 0, 0, 0);
    }

    // online softmax per wave-owned rows
#pragma unroll
    for (int mi = 0; mi < 2; mi++) {
      float rmax[4];
#pragma unroll
      for (int r = 0; r < 4; r++) {
        int grow = q0 + wave * 32 + mi * 16 + lq * 4 + r;
        float mx = -__builtin_inff();
#pragma unroll
        for (int ni = 0; ni < 4; ni++) {
          float s = sacc[mi][ni][r] * SC;
          int gcol = kv0 + ni * 16 + lr;
          if (gcol > grow) s = -__builtin_inff();
          sacc[mi][ni][r] = s;
          mx = fmaxf(mx, s);
        }
        mx = fmaxf(mx, __shfl_xor(mx, 1));
        mx = fmaxf(mx, __shfl_xor(mx, 2));
        mx = fmaxf(mx, __shfl_xor(mx, 4));
        mx = fmaxf(mx, __shfl_xor(mx, 8));
        rmax[r] = mx;
      }
#pragma unroll
      for (int r = 0; r < 4; r++) {
        float mold = mstate[mi][r];
        float mnew = fmaxf(mold, rmax[r]);
        float alpha = exp2f(mold - mnew);
        float rs = 0.f;
#pragma unroll
        for (int ni = 0; ni < 4; ni++) {
          float p = exp2f(sacc[mi][ni][r] - mnew);
          sacc[mi][ni][r] = p;
          rs += p;
        }
        rs += __shfl_xor(rs, 1); rs += __shfl_xor(rs, 2);
        rs += __shfl_xor(rs, 4); rs += __shfl_xor(rs, 8);
        lstate[mi][r] = lstate[mi][r] * alpha + rs;
        mstate[mi][r] = mnew;
#pragma unroll
        for (int ni = 0; ni < 8; ni++) oacc[mi][ni][r] *= alpha;
      }
      // P -> LDS (C/D layout write); wave-private region, no barrier needed
#pragma unroll
      for (int ni = 0; ni < 4; ni++)
#pragma unroll
        for (int r = 0; r < 4; r++)
          Ps[wave * 32 + mi * 16 + lq * 4 + r][ni * 16 + lr] = f2b(sacc[mi][ni][r]);
    }

    // O += P * V  (P: 32x64 A-layout from LDS, V^T for B operand)
#pragma unroll
    for (int k2 = 0; k2 < 2; k2++) {
      bf16x8 pf[2];
#pragma unroll
      for (int mi = 0; mi < 2; mi++)
        pf[mi] = *(const bf16x8*)(&Ps[wave * 32 + mi * 16 + lr][k2 * 32 + lq * 8]);
#pragma unroll
      for (int ni = 0; ni < 8; ni++) {
        bf16x8 vf = *(const bf16x8*)(&Vts[ni * 16 + lr][k2 * 32 + lq * 8]);
#pragma unroll
        for (int mi = 0; mi < 2; mi++)
          oacc[mi][ni] = __builtin_amdgcn_mfma_f32_16x16x32_bf16(pf[mi], vf, oacc[mi][ni], 0, 0, 0);
      }
    }
    __syncthreads();
  }

  // epilogue: O /= l, write bf16
#pragma unroll
  for (int mi = 0; mi < 2; mi++)
#pragma unroll
    for (int r = 0; r < 4; r++) {
      float inv = 1.0f / lstate[mi][r];
      int grow = q0 + wave * 32 + mi * 16 + lq * 4 + r;
      size_t base = ((size_t)b * T + grow) * 2048 + (size_t)h * 128;
#pragma unroll
      for (int ni = 0; ni < 8; ni++)
        O[base + ni * 16 + lr] = f2b(oacc[mi][ni][r] * inv);
    }
}

// ---------------- launcher ----------------
extern "C" void kernel_launch(void* const* d_in, const int* in_sizes, int n_in,
                              void* d_out, int out_size, void* d_ws, size_t ws_size,
                              hipStream_t stream) {
  const float* hs   = (const float*)d_in[0];
  const float* cosp = (const float*)d_in[1];
  const float* sinp = (const float*)d_in[2];
  const float* wq   = (const float*)d_in[3];
  const float* wk   = (const float*)d_in[4];
  const float* wv   = (const float*)d_in[5];
  const float* wo   = (const float*)d_in[6];
  float* out = (float*)d_out;

  char* p = (char*)d_ws;
  ushort* hs_b = (ushort*)p; p += (size_t)8192 * 2048 * 2;
  ushort* q_b  = (ushort*)p; p += (size_t)8192 * 2048 * 2;
  ushort* k_b  = (ushort*)p; p += (size_t)8192 * 512 * 2;
  ushort* v_b  = (ushort*)p; p += (size_t)8192 * 512 * 2;
  ushort* o_b  = (ushort*)p; p += (size_t)8192 * 2048 * 2;
  ushort* wq_b = (ushort*)p; p += (size_t)2048 * 2048 * 2;
  ushort* wk_b = (ushort*)p; p += (size_t)512 * 2048 * 2;
  ushort* wv_b = (ushort*)p; p += (size_t)512 * 2048 * 2;
  ushort* wo_b = (ushort*)p; p += (size_t)2048 * 2048 * 2;

  // conversions
  cvt_kernel<<<16384, 256, 0, stream>>>(hs, hs_b, 4194304);
  cvt_kernel<<<4096, 256, 0, stream>>>(wq, wq_b, 1048576);
  cvt_kernel<<<1024, 256, 0, stream>>>(wk, wk_b, 262144);
  cvt_kernel<<<1024, 256, 0, stream>>>(wv, wv_b, 262144);
  cvt_kernel<<<4096, 256, 0, stream>>>(wo, wo_b, 1048576);

  // projections
  gemm_nt<false><<<dim3(64, 16), 256, 0, stream>>>(hs_b, wq_b, q_b, 8192, 2048, 2048);
  gemm_nt<false><<<dim3(64, 4), 256, 0, stream>>>(hs_b, wk_b, k_b, 8192, 512, 2048);
  gemm_nt<false><<<dim3(64, 4), 256, 0, stream>>>(hs_b, wv_b, v_b, 8192, 512, 2048);

  // rope
  rope_kernel<<<32768, 256, 0, stream>>>(q_b, cosp, sinp, 16, 8388608);
  rope_kernel<<<8192, 256, 0, stream>>>(k_b, cosp, sinp, 4, 2097152);

  // attention
  attn_kernel<<<dim3(16, 16, 4), 256, 0, stream>>>(q_b, k_b, v_b, o_b);

  // output projection (fp32 out)
  gemm_nt<true><<<dim3(64, 16), 256, 0, stream>>>(o_b, wo_b, out, 8192, 2048, 2048);
}